// Round 1
// baseline (554.998 us; speedup 1.0000x reference)
//
#include <hip/hip_runtime.h>
#include <math.h>

#define BB 2
#define NN 2048
#define EE 256
#define HH 8
#define DD 32

// ---------------------------------------------------------------------------
// Generic fp32 GEMM: C[m,n] = sum_k A[m,k] * W[n,k] + bias[n] (+ resid[m,n])
// A: (4096 x 256) row-major, W: (Ncols x 256) row-major.
// 64x64 tile per block, BK=16, 4x4 per thread, 256 threads.
// ---------------------------------------------------------------------------
__global__ __launch_bounds__(256) void gemm_kernel(const float* __restrict__ A,
                                                   const float* __restrict__ W,
                                                   const float* __restrict__ bias,
                                                   const float* __restrict__ resid,
                                                   float* __restrict__ C,
                                                   int Ncols) {
  __shared__ float As[64][17];
  __shared__ float Ws[64][17];
  int tid = threadIdx.x;
  int tx = tid & 15, ty = tid >> 4;
  int rowBase = blockIdx.y * 64;
  int colBase = blockIdx.x * 64;
  float acc[4][4] = {};
  for (int k0 = 0; k0 < EE; k0 += 16) {
#pragma unroll
    for (int t = 0; t < 4; ++t) {
      int idx = tid + t * 256;
      int r = idx >> 4, c = idx & 15;
      As[r][c] = A[(size_t)(rowBase + r) * EE + k0 + c];
      Ws[r][c] = W[(size_t)(colBase + r) * EE + k0 + c];
    }
    __syncthreads();
#pragma unroll
    for (int kk = 0; kk < 16; ++kk) {
      float a[4], w[4];
#pragma unroll
      for (int i = 0; i < 4; ++i) a[i] = As[ty * 4 + i][kk];
#pragma unroll
      for (int j = 0; j < 4; ++j) w[j] = Ws[tx * 4 + j][kk];
#pragma unroll
      for (int i = 0; i < 4; ++i)
#pragma unroll
        for (int j = 0; j < 4; ++j)
          acc[i][j] = fmaf(a[i], w[j], acc[i][j]);
    }
    __syncthreads();
  }
#pragma unroll
  for (int i = 0; i < 4; ++i) {
    int row = rowBase + ty * 4 + i;
#pragma unroll
    for (int j = 0; j < 4; ++j) {
      int col = colBase + tx * 4 + j;
      float v = acc[i][j] + bias[col];
      if (resid) v += resid[(size_t)row * Ncols + col];
      C[(size_t)row * Ncols + col] = v;
    }
  }
}

// ---------------------------------------------------------------------------
// tau[b,n,h] = dot(feat[b,n,:], tau_w[h,:]) + tau_b[h]
// one thread per (row, h); 32768 threads.
// ---------------------------------------------------------------------------
__global__ __launch_bounds__(256) void tau_kernel(const float* __restrict__ feat,
                                                  const float* __restrict__ tau_w,
                                                  const float* __restrict__ tau_b,
                                                  float* __restrict__ tau) {
  int idx = blockIdx.x * 256 + threadIdx.x;
  int row = idx >> 3, h = idx & 7;
  const float4* f = (const float4*)(feat + (size_t)row * EE);
  const float4* w = (const float4*)(tau_w + (size_t)h * EE);
  float s = 0.f;
#pragma unroll 8
  for (int e = 0; e < EE / 4; ++e) {
    float4 a = f[e], b4 = w[e];
    s = fmaf(a.x, b4.x, s);
    s = fmaf(a.y, b4.y, s);
    s = fmaf(a.z, b4.z, s);
    s = fmaf(a.w, b4.w, s);
  }
  tau[idx] = s + tau_b[h];
}

// ---------------------------------------------------------------------------
// Flash attention with distance mask.
// grid = (B*H, N/128); block = 256 threads.
// Each pair of threads handles one query row (d split 16+16).
// j-tiles of 64 staged in LDS (K, V, centers).
// ---------------------------------------------------------------------------
__global__ __launch_bounds__(256) void attn_kernel(const float* __restrict__ qkv,
                                                   const float* __restrict__ bbox,
                                                   const float* __restrict__ tau,
                                                   float* __restrict__ o_out) {
  __shared__ float4 Ks[64][8];
  __shared__ float4 Vs[64][8];
  __shared__ float Cx[64], Cy[64];

  int bh = blockIdx.x;
  int b = bh >> 3, h = bh & 7;
  int tid = threadIdx.x;
  int half = tid & 1;
  int li = tid >> 1;                   // 0..127
  int i = blockIdx.y * 128 + li;       // query row within (b)
  size_t rowq = (size_t)b * NN + i;

  float4 q[4];
  const float4* qp = (const float4*)(qkv + rowq * 768 + h * DD + half * 16);
#pragma unroll
  for (int t = 0; t < 4; ++t) q[t] = qp[t];

  float taui = tau[rowq * HH + h];
  float cxi = bbox[rowq * 4 + 0];
  float cyi = bbox[rowq * 4 + 1];
  const float rs = 0.17677669529663687f;  // 1/sqrt(32)

  float m = -INFINITY, l = 0.f;
  float o[16] = {};

  for (int j0 = 0; j0 < NN; j0 += 64) {
#pragma unroll
    for (int t = 0; t < 2; ++t) {
      int fi = tid + t * 256;           // 0..511
      int j = fi >> 3, dq = fi & 7;
      const float* base = qkv + ((size_t)b * NN + j0 + j) * 768 + EE + h * DD + dq * 4;
      Ks[j][dq] = *(const float4*)base;
      Vs[j][dq] = *(const float4*)(base + EE);
    }
    if (tid < 64) {
      Cx[tid] = bbox[((size_t)b * NN + j0 + tid) * 4 + 0];
      Cy[tid] = bbox[((size_t)b * NN + j0 + tid) * 4 + 1];
    }
    __syncthreads();

    for (int jj = 0; jj < 64; ++jj) {
      float s = 0.f;
#pragma unroll
      for (int dq = 0; dq < 4; ++dq) {
        float4 kv = Ks[jj][half * 4 + dq];
        s = fmaf(q[dq].x, kv.x, s);
        s = fmaf(q[dq].y, kv.y, s);
        s = fmaf(q[dq].z, kv.z, s);
        s = fmaf(q[dq].w, kv.w, s);
      }
      s += __shfl_xor(s, 1);
      float dx = cxi - Cx[jj], dy = cyi - Cy[jj];
      s = fmaf(s, rs, -sqrtf(dx * dx + dy * dy) * taui);

      float mn = fmaxf(m, s);
      float scale = __expf(m - mn);
      float p = __expf(s - mn);
      l = fmaf(l, scale, p);
#pragma unroll
      for (int dq = 0; dq < 4; ++dq) {
        float4 v = Vs[jj][half * 4 + dq];
        o[dq * 4 + 0] = fmaf(o[dq * 4 + 0], scale, p * v.x);
        o[dq * 4 + 1] = fmaf(o[dq * 4 + 1], scale, p * v.y);
        o[dq * 4 + 2] = fmaf(o[dq * 4 + 2], scale, p * v.z);
        o[dq * 4 + 3] = fmaf(o[dq * 4 + 3], scale, p * v.w);
      }
      m = mn;
    }
    __syncthreads();
  }

  float inv = 1.f / l;
  float4* op = (float4*)(o_out + rowq * EE + h * DD + half * 16);
#pragma unroll
  for (int t = 0; t < 4; ++t) {
    float4 v;
    v.x = o[t * 4 + 0] * inv;
    v.y = o[t * 4 + 1] * inv;
    v.z = o[t * 4 + 2] * inv;
    v.w = o[t * 4 + 3] * inv;
    op[t] = v;
  }
}

extern "C" void kernel_launch(void* const* d_in, const int* in_sizes, int n_in,
                              void* d_out, int out_size, void* d_ws, size_t ws_size,
                              hipStream_t stream) {
  const float* bbox  = (const float*)d_in[0];
  const float* feat  = (const float*)d_in[1];
  const float* in_w  = (const float*)d_in[2];
  const float* in_b  = (const float*)d_in[3];
  const float* out_w = (const float*)d_in[4];
  const float* out_b = (const float*)d_in[5];
  const float* tau_w = (const float*)d_in[6];
  const float* tau_b = (const float*)d_in[7];
  float* out = (float*)d_out;

  float* ws  = (float*)d_ws;
  float* qkv = ws;                                   // 4096*768
  float* tau = qkv + (size_t)BB * NN * 3 * EE;       // 4096*8
  float* o   = tau + (size_t)BB * NN * HH;           // 4096*256

  // QKV projection: (4096 x 256) @ (768 x 256)^T + bias
  gemm_kernel<<<dim3(768 / 64, (BB * NN) / 64), 256, 0, stream>>>(
      feat, in_w, in_b, nullptr, qkv, 3 * EE);

  // tau
  tau_kernel<<<dim3((BB * NN * HH) / 256), 256, 0, stream>>>(feat, tau_w, tau_b, tau);

  // attention
  attn_kernel<<<dim3(BB * HH, NN / 128), 256, 0, stream>>>(qkv, bbox, tau, o);

  // out projection + bias + residual
  gemm_kernel<<<dim3(EE / 64, (BB * NN) / 64), 256, 0, stream>>>(
      o, out_w, out_b, feat, out, EE);
}

// Round 3
// 176.310 us; speedup vs baseline: 3.1479x; 3.1479x over previous
//
#include <hip/hip_runtime.h>
#include <math.h>

#define BB 2
#define NN 2048
#define EE 256
#define HH 8
#define DD 32

typedef __attribute__((ext_vector_type(8))) short short8;
typedef __attribute__((ext_vector_type(4))) short short4v;
typedef __attribute__((ext_vector_type(4))) float f32x4;

__device__ inline unsigned short f2bf(float f) {
  union { float f; unsigned int u; } a; a.f = f;
  unsigned int r = a.u + 0x7FFFu + ((a.u >> 16) & 1u);
  return (unsigned short)(r >> 16);
}

// ---------------------------------------------------------------------------
// QKV projection GEMM: qkvb[row][col] = bf16(A@W^T + b), also V^T per head:
// vt[(b*8+h)*32+d][n].  A:(4096x256) f32, W:(768x256) f32.
// 64x64 tile, BK=16, 4x4/thread, 256 threads.
// ---------------------------------------------------------------------------
__global__ __launch_bounds__(256) void gemm_qkv_kernel(const float* __restrict__ A,
                                                       const float* __restrict__ W,
                                                       const float* __restrict__ bias,
                                                       unsigned short* __restrict__ qkvb,
                                                       unsigned short* __restrict__ vt) {
  __shared__ float As[64][17];
  __shared__ float Ws[64][17];
  int tid = threadIdx.x;
  int tx = tid & 15, ty = tid >> 4;
  int rowBase = blockIdx.y * 64;
  int colBase = blockIdx.x * 64;
  float acc[4][4] = {};
  for (int k0 = 0; k0 < EE; k0 += 16) {
#pragma unroll
    for (int t = 0; t < 4; ++t) {
      int idx = tid + t * 256;
      int r = idx >> 4, c = idx & 15;
      As[r][c] = A[(size_t)(rowBase + r) * EE + k0 + c];
      Ws[r][c] = W[(size_t)(colBase + r) * EE + k0 + c];
    }
    __syncthreads();
#pragma unroll
    for (int kk = 0; kk < 16; ++kk) {
      float a[4], w[4];
#pragma unroll
      for (int i = 0; i < 4; ++i) a[i] = As[ty * 4 + i][kk];
#pragma unroll
      for (int j = 0; j < 4; ++j) w[j] = Ws[tx * 4 + j][kk];
#pragma unroll
      for (int i = 0; i < 4; ++i)
#pragma unroll
        for (int j = 0; j < 4; ++j)
          acc[i][j] = fmaf(a[i], w[j], acc[i][j]);
    }
    __syncthreads();
  }
  unsigned short bv[4][4];
#pragma unroll
  for (int i = 0; i < 4; ++i)
#pragma unroll
    for (int j = 0; j < 4; ++j)
      bv[i][j] = f2bf(acc[i][j] + bias[colBase + tx * 4 + j]);

  // qkvb stores: row-major, 4 cols packed
#pragma unroll
  for (int i = 0; i < 4; ++i) {
    int row = rowBase + ty * 4 + i;
    ushort4 u;
    u.x = bv[i][0]; u.y = bv[i][1]; u.z = bv[i][2]; u.w = bv[i][3];
    *(ushort4*)(qkvb + (size_t)row * 768 + colBase + tx * 4) = u;
  }
  // vt stores for the V third (cols 512..767): vt[(b*8+h)*32+d][n]
  if (colBase >= 512) {
    int rowb = rowBase + ty * 4;
    int b = rowb >> 11, n = rowb & 2047;
#pragma unroll
    for (int j = 0; j < 4; ++j) {
      int hd = colBase + tx * 4 + j - 512;
      ushort4 u;
      u.x = bv[0][j]; u.y = bv[1][j]; u.z = bv[2][j]; u.w = bv[3][j];
      *(ushort4*)(vt + ((size_t)(b * 8 + (hd >> 5)) * 32 + (hd & 31)) * NN + n) = u;
    }
  }
}

// ---------------------------------------------------------------------------
// tau2[row][h] = (dot(feat,tau_w[h]) + tau_b[h]) * log2e;  cxy[row] = centers
// ---------------------------------------------------------------------------
__global__ __launch_bounds__(256) void tau_cxy_kernel(const float* __restrict__ feat,
                                                      const float* __restrict__ tau_w,
                                                      const float* __restrict__ tau_b,
                                                      const float* __restrict__ bbox,
                                                      float* __restrict__ tau2,
                                                      float2* __restrict__ cxy) {
  int idx = blockIdx.x * 256 + threadIdx.x;
  int row = idx >> 3, h = idx & 7;
  const float4* f = (const float4*)(feat + (size_t)row * EE);
  const float4* w = (const float4*)(tau_w + (size_t)h * EE);
  float s = 0.f;
#pragma unroll 8
  for (int e = 0; e < EE / 4; ++e) {
    float4 a = f[e], b4 = w[e];
    s = fmaf(a.x, b4.x, s);
    s = fmaf(a.y, b4.y, s);
    s = fmaf(a.z, b4.z, s);
    s = fmaf(a.w, b4.w, s);
  }
  tau2[idx] = (s + tau_b[h]) * 1.4426950408889634f;
  if (h == 0) {
    float2 c;
    c.x = bbox[(size_t)row * 4 + 0];
    c.y = bbox[(size_t)row * 4 + 1];
    cxy[row] = c;
  }
}

// ---------------------------------------------------------------------------
// MFMA flash attention. One wave (64 thr) per block; 16 queries per wave.
// grid = (B*H, N/16). No LDS, no barriers: K / V^T / centers stream via L2.
// S^T = K·Q^T (16x16x32 MFMA, q = lane&15 -> softmax state lane-local);
// PV:  O^T = V^T·P^T with permuted k-slots so S^T C-layout feeds B directly.
// ---------------------------------------------------------------------------
__global__ __launch_bounds__(64) void attn_kernel(const unsigned short* __restrict__ qkvb,
                                                  const unsigned short* __restrict__ vt,
                                                  const float2* __restrict__ cxy,
                                                  const float* __restrict__ tau2,
                                                  float* __restrict__ o_out) {
  int bh = blockIdx.x;
  int b = bh >> 3, h = bh & 7;
  int qt = blockIdx.y;
  int lane = threadIdx.x;
  int q15 = lane & 15, g = lane >> 4;
  int rowq = b * NN + qt * 16 + q15;

  short8 qf = *(const short8*)(qkvb + (size_t)rowq * 768 + h * 32 + g * 8);
  float2 ci = cxy[rowq];
  float t2 = tau2[(size_t)rowq * HH + h];
  const float rs2 = 0.17677669529663687f * 1.4426950408889634f;  // 1/sqrt(32)*log2e

  float m = -INFINITY, l = 0.f;
  f32x4 acc0 = {0.f, 0.f, 0.f, 0.f}, acc1 = {0.f, 0.f, 0.f, 0.f};

  const unsigned short* kp = qkvb + (size_t)b * NN * 768 + 256 + h * 32 + (size_t)q15 * 768 + g * 8;
  const unsigned short* vbase = vt + (size_t)bh * 32 * NN;
  const float2* cb = cxy + b * NN;

  for (int j0 = 0; j0 < NN; j0 += 64) {
    // ---- S^T tiles: 4x mfma 16x16x32 (A = K rows, B = Q) ----
    f32x4 st[4];
#pragma unroll
    for (int t = 0; t < 4; ++t) {
      short8 kf = *(const short8*)(kp + (size_t)(j0 + t * 16) * 768);
      st[t] = __builtin_amdgcn_mfma_f32_16x16x32_bf16(kf, qf, (f32x4){0.f, 0.f, 0.f, 0.f}, 0, 0, 0);
    }
    // ---- V^T frags (issue loads early) ----
    union { short8 v; short4v h2[2]; } vf[2][2];
#pragma unroll
    for (int t2i = 0; t2i < 2; ++t2i)
#pragma unroll
      for (int dh = 0; dh < 2; ++dh) {
        const unsigned short* vr = vbase + (size_t)(dh * 16 + q15) * NN + j0 + t2i * 32 + g * 4;
        vf[t2i][dh].h2[0] = *(const short4v*)(vr);
        vf[t2i][dh].h2[1] = *(const short4v*)(vr + 16);
      }
    // ---- mask + online softmax (per lane: 16 scores, its own q) ----
    float s[16];
    float tmax = -INFINITY;
#pragma unroll
    for (int t = 0; t < 4; ++t) {
      float4 c01 = *(const float4*)(cb + j0 + t * 16 + g * 4);
      float4 c23 = *(const float4*)(cb + j0 + t * 16 + g * 4 + 2);
      float cx[4] = {c01.x, c01.z, c23.x, c23.z};
      float cy[4] = {c01.y, c01.w, c23.y, c23.w};
#pragma unroll
      for (int r = 0; r < 4; ++r) {
        float dx = ci.x - cx[r], dy = ci.y - cy[r];
        float dist = __builtin_amdgcn_sqrtf(fmaf(dy, dy, dx * dx));
        float e = fmaf(st[t][r], rs2, -dist * t2);
        s[t * 4 + r] = e;
        tmax = fmaxf(tmax, e);
      }
    }
    tmax = fmaxf(tmax, __shfl_xor(tmax, 16));
    tmax = fmaxf(tmax, __shfl_xor(tmax, 32));
    float mn = fmaxf(m, tmax);
    float scale = __builtin_amdgcn_exp2f(m - mn);
    m = mn;
    float p[16], lsum = 0.f;
#pragma unroll
    for (int i = 0; i < 16; ++i) {
      p[i] = __builtin_amdgcn_exp2f(s[i] - mn);
      lsum += p[i];
    }
    l = fmaf(l, scale, lsum);
#pragma unroll
    for (int r = 0; r < 4; ++r) { acc0[r] *= scale; acc1[r] *= scale; }
    // ---- pack P to bf16 B-frags (k-slot order matches vf loads) ----
    union { short8 v; unsigned int u[4]; } pf[2];
#pragma unroll
    for (int t2i = 0; t2i < 2; ++t2i)
#pragma unroll
      for (int w = 0; w < 4; ++w) {
        float lo = p[(t2i * 2 + (w >> 1)) * 4 + (w & 1) * 2];
        float hi = p[(t2i * 2 + (w >> 1)) * 4 + (w & 1) * 2 + 1];
        asm("v_cvt_pk_bf16_f32 %0, %1, %2" : "=v"(pf[t2i].u[w]) : "v"(lo), "v"(hi));
      }
    // ---- PV: 4x mfma, acc in O^T layout (col=q, row=d) ----
    acc0 = __builtin_amdgcn_mfma_f32_16x16x32_bf16(vf[0][0].v, pf[0].v, acc0, 0, 0, 0);
    acc1 = __builtin_amdgcn_mfma_f32_16x16x32_bf16(vf[0][1].v, pf[0].v, acc1, 0, 0, 0);
    acc0 = __builtin_amdgcn_mfma_f32_16x16x32_bf16(vf[1][0].v, pf[1].v, acc0, 0, 0, 0);
    acc1 = __builtin_amdgcn_mfma_f32_16x16x32_bf16(vf[1][1].v, pf[1].v, acc1, 0, 0, 0);
  }

  // l currently holds only this lane's 16-of-64 keys per tile; the MFMA acc
  // holds the FULL key-sum. Reduce l across the 4 g-lanes sharing this query.
  l += __shfl_xor(l, 16);
  l += __shfl_xor(l, 32);

  float inv = 1.f / l;
  float4 o0, o1;
  o0.x = acc0[0] * inv; o0.y = acc0[1] * inv; o0.z = acc0[2] * inv; o0.w = acc0[3] * inv;
  o1.x = acc1[0] * inv; o1.y = acc1[1] * inv; o1.z = acc1[2] * inv; o1.w = acc1[3] * inv;
  float* ob = o_out + (size_t)rowq * EE + h * 32;
  *(float4*)(ob + g * 4) = o0;
  *(float4*)(ob + 16 + g * 4) = o1;
}

// ---------------------------------------------------------------------------
// Out projection (fp32): C = A@W^T + b + resid
// ---------------------------------------------------------------------------
__global__ __launch_bounds__(256) void gemm_out_kernel(const float* __restrict__ A,
                                                       const float* __restrict__ W,
                                                       const float* __restrict__ bias,
                                                       const float* __restrict__ resid,
                                                       float* __restrict__ C) {
  __shared__ float As[64][17];
  __shared__ float Ws[64][17];
  int tid = threadIdx.x;
  int tx = tid & 15, ty = tid >> 4;
  int rowBase = blockIdx.y * 64;
  int colBase = blockIdx.x * 64;
  float acc[4][4] = {};
  for (int k0 = 0; k0 < EE; k0 += 16) {
#pragma unroll
    for (int t = 0; t < 4; ++t) {
      int idx = tid + t * 256;
      int r = idx >> 4, c = idx & 15;
      As[r][c] = A[(size_t)(rowBase + r) * EE + k0 + c];
      Ws[r][c] = W[(size_t)(colBase + r) * EE + k0 + c];
    }
    __syncthreads();
#pragma unroll
    for (int kk = 0; kk < 16; ++kk) {
      float a[4], w[4];
#pragma unroll
      for (int i = 0; i < 4; ++i) a[i] = As[ty * 4 + i][kk];
#pragma unroll
      for (int j = 0; j < 4; ++j) w[j] = Ws[tx * 4 + j][kk];
#pragma unroll
      for (int i = 0; i < 4; ++i)
#pragma unroll
        for (int j = 0; j < 4; ++j)
          acc[i][j] = fmaf(a[i], w[j], acc[i][j]);
    }
    __syncthreads();
  }
#pragma unroll
  for (int i = 0; i < 4; ++i) {
    int row = rowBase + ty * 4 + i;
#pragma unroll
    for (int j = 0; j < 4; ++j) {
      int col = colBase + tx * 4 + j;
      float v = acc[i][j] + bias[col] + resid[(size_t)row * EE + col];
      C[(size_t)row * EE + col] = v;
    }
  }
}

extern "C" void kernel_launch(void* const* d_in, const int* in_sizes, int n_in,
                              void* d_out, int out_size, void* d_ws, size_t ws_size,
                              hipStream_t stream) {
  const float* bbox  = (const float*)d_in[0];
  const float* feat  = (const float*)d_in[1];
  const float* in_w  = (const float*)d_in[2];
  const float* in_b  = (const float*)d_in[3];
  const float* out_w = (const float*)d_in[4];
  const float* out_b = (const float*)d_in[5];
  const float* tau_w = (const float*)d_in[6];
  const float* tau_b = (const float*)d_in[7];
  float* out = (float*)d_out;

  float* o = (float*)d_ws;                                   // 1,048,576 f32
  unsigned short* qkvb = (unsigned short*)(o + 1048576);     // 3,145,728 bf16
  unsigned short* vt = qkvb + 3145728;                       // 1,048,576 bf16
  float* tau2 = (float*)(vt + 1048576);                      // 32,768 f32
  float2* cxy = (float2*)(tau2 + 32768);                     // 4,096 float2

  gemm_qkv_kernel<<<dim3(12, 64), 256, 0, stream>>>(feat, in_w, in_b, qkvb, vt);
  tau_cxy_kernel<<<dim3(128), 256, 0, stream>>>(feat, tau_w, tau_b, bbox, tau2, cxy);
  attn_kernel<<<dim3(BB * HH, NN / 16), 64, 0, stream>>>(qkvb, vt, cxy, tau2, o);
  gemm_out_kernel<<<dim3(EE / 64, (BB * NN) / 64), 256, 0, stream>>>(o, out_w, out_b, feat, out);
}